// Round 16
// baseline (424.195 us; speedup 1.0000x reference)
//
#include <hip/hip_runtime.h>

#define NN 20000
#define TT 2
#define HH 128
#define LL 4
#define EE 320000
#define FF 514
#define CN 3
#define CG 2
#define MP 20096  // rows per ti-half, padded to multiple of 128

typedef __bf16 bf16x8 __attribute__((ext_vector_type(8)));
typedef __bf16 bf16x4 __attribute__((ext_vector_type(4)));
typedef __bf16 bf16x2 __attribute__((ext_vector_type(2)));
typedef float f32x4 __attribute__((ext_vector_type(4)));

struct __align__(4) Edge4 { unsigned short src; signed char q0, q1; };  // ea*16

// ---------------- wave helpers ----------------
__device__ inline float wave_sum(float v) {
#pragma unroll
  for (int off = 32; off; off >>= 1) v += __shfl_xor(v, off);
  return v;
}
__device__ inline float red16(float v) {  // reduce across fr = lane&15
  v += __shfl_xor(v, 1); v += __shfl_xor(v, 2);
  v += __shfl_xor(v, 4); v += __shfl_xor(v, 8);
  return v;
}

__device__ __forceinline__ float fexp2(float x) {
#if __has_builtin(__builtin_amdgcn_exp2f)
  return __builtin_amdgcn_exp2f(x);
#else
  return exp2f(x);
#endif
}

__device__ __forceinline__ void gload_lds16(const void* g, void* l) {
  __builtin_amdgcn_global_load_lds(
      (const __attribute__((address_space(1))) unsigned int*)g,
      (__attribute__((address_space(3))) unsigned int*)l, 16, 0, 0);
}

// ---------------- fused encoder GEMM (f32 A, async+swizzled) + scatter ------
// A staged f32 via global_load_lds into linear LDS; the 16B-chunk column is
// XOR-swizzled in the GLOBAL source address (m173 pattern) so fragment reads
// are ~2-way banked. Rows clamped to NN-1 (outputs masked); B zero-padded for
// k>=514 so tail garbage contributes exactly 0.
#define ENCB (MP / 64)
#define SSB 313   // ceil(2*EE / (256*8))
#define CHUNK 5000  // 2*NN/8 gnodes per XCD chunk
__global__ __launch_bounds__(256) void enc_scatter_kernel(
    const float* __restrict__ Af, const __bf16* __restrict__ BT,
    const float* __restrict__ bias, __bf16* __restrict__ C,
    const int* __restrict__ edge_index, const float* __restrict__ edge_attr,
    int* __restrict__ cursor, Edge4* __restrict__ edges) {
  __shared__ float Asf[2][64][32];
  __shared__ __bf16 Bs[2][128][32];
  const int tid = threadIdx.x;
  if (blockIdx.x >= ENCB) {
    int sb = blockIdx.x - ENCB;
    int chunk = sb & 7;
    int slice = sb >> 3;
    int i0 = slice * 2048 + tid * 8;
    if (i0 >= 2 * EE) return;
    int ti = (i0 >= EE) ? 1 : 0;
    int e0 = i0 - ti * EE;
    const int* srcp = edge_index + (size_t)ti * 2 * EE;
    int dst8[8];
    __builtin_memcpy(dst8, srcp + EE + e0, 32);
#pragma unroll
    for (int j = 0; j < 8; ++j) {
      int gnode = ti * NN + dst8[j];
      if (gnode / CHUNK != chunk) continue;
      int s = srcp[e0 + j];
      float2 ea = ((const float2*)edge_attr)[(size_t)ti * EE + e0 + j];
      int pos = atomicAdd(&cursor[gnode], 1);
      Edge4 ed;
      ed.src = (unsigned short)(s + ti * MP);
      int q0 = (int)rintf(fminf(fmaxf(ea.x * 16.f, -127.f), 127.f));
      int q1 = (int)rintf(fminf(fmaxf(ea.y * 16.f, -127.f), 127.f));
      ed.q0 = (signed char)q0;
      ed.q1 = (signed char)q1;
      __builtin_memcpy(&edges[pos], &ed, sizeof(Edge4));
    }
    return;
  }
  const int K = 576;
  const int lane = tid & 63, w = tid >> 6;
  const int bm = blockIdx.x * 64;
  const int wr = (w >> 1) * 32, wc = (w & 1) * 64;
  const int fr = lane & 15, fq = lane >> 4;
  const int rowA = tid >> 2, chA = (tid & 3) * 8;  // B staging (bf16)
  // A staging (f32): thread t owns LDS chunks t and t+256 (16B each)
  const int arow0 = tid >> 3, acc0 = tid & 7;
  const int arow1 = (tid + 256) >> 3, acc1 = (tid + 256) & 7;
  const float* Ar0 = Af + (size_t)min(bm + arow0, NN - 1) * FF +
                     (acc0 ^ (arow0 & 7)) * 4;
  const float* Ar1 = Af + (size_t)min(bm + arow1, NN - 1) * FF +
                     (acc1 ^ (arow1 & 7)) * 4;
  const __bf16* Bb = BT + (size_t)rowA * K + chA;
  const __bf16* Bb2 = Bb + (size_t)64 * K;
  f32x4 acc[2][4] = {};

#define STAGE(buf, k0)                                        \
  do {                                                        \
    gload_lds16(Ar0 + (k0), &Asf[buf][arow0][(tid & 7) * 4]); \
    gload_lds16(Ar1 + (k0), &Asf[buf][arow1][(tid & 7) * 4]); \
    gload_lds16(Bb + (k0), &Bs[buf][rowA][chA]);              \
    gload_lds16(Bb2 + (k0), &Bs[buf][rowA + 64][chA]);        \
  } while (0)

  STAGE(0, 0);
  __syncthreads();
  int cur = 0;
  for (int k0 = 0; k0 < K; k0 += 32) {
    if (k0 + 32 < K) STAGE(cur ^ 1, k0 + 32);
    bf16x8 af[2], bq[4];
#pragma unroll
    for (int m = 0; m < 2; ++m) {
      int rr = wr + m * 16 + fr;
      int sw = rr & 7;
      f32x4 a0 = *(const f32x4*)&Asf[cur][rr][((fq * 2) ^ sw) * 4];
      f32x4 a1 = *(const f32x4*)&Asf[cur][rr][((fq * 2 + 1) ^ sw) * 4];
#pragma unroll
      for (int i = 0; i < 4; ++i) {
        af[m][i] = (__bf16)a0[i];
        af[m][4 + i] = (__bf16)a1[i];
      }
    }
#pragma unroll
    for (int n = 0; n < 4; ++n)
      bq[n] = *(const bf16x8*)&Bs[cur][wc + n * 16 + fr][fq * 8];
#pragma unroll
    for (int m = 0; m < 2; ++m)
#pragma unroll
      for (int n = 0; n < 4; ++n)
        acc[m][n] =
            __builtin_amdgcn_mfma_f32_16x16x32_bf16(af[m], bq[n], acc[m][n], 0, 0, 0);
    __syncthreads();
    cur ^= 1;
  }
#undef STAGE
#pragma unroll
  for (int m = 0; m < 2; ++m) {
#pragma unroll
    for (int n = 0; n < 4; ++n) {
#pragma unroll
      for (int j = 0; j < 4; ++j) {
        int gm = bm + wr + m * 16 + fq * 4 + j;
        int gn = wc + n * 16 + fr;
        if (gm < NN) {
          __bf16 c = (__bf16)(acc[m][n][j] + bias[gn]);
          C[(size_t)gm * 128 + gn] = c;
          C[(size_t)(gm + MP) * 128 + gn] = c;
        }
      }
    }
  }
}

// ---------------- fused layer MLP: lin1+LN+relu (LDS) -> lin2+res+LN -------
template <int MODE>
__global__ __launch_bounds__(256) void gemm_layer(
    const __bf16* __restrict__ A, const __bf16* __restrict__ W1T,
    const float* __restrict__ b1, const float* __restrict__ g1,
    const float* __restrict__ be1, const __bf16* __restrict__ W2T,
    const float* __restrict__ b2, float* __restrict__ xres,
    const float* __restrict__ dgv, const float* __restrict__ dbv,
    void* __restrict__ lnout) {
  __shared__ char smem[40960];
  __shared__ __bf16 h1[64][264];
  __shared__ float redS[64][2], redS2[64][2];
  auto As = (__bf16(*)[64][32])smem;
  auto Bs1 = (__bf16(*)[256][32])(smem + 8192);
  auto Bs2 = (__bf16(*)[128][32])smem;
  const int tid = threadIdx.x;
  const int lane = tid & 63, w = tid >> 6;
  const int bm = blockIdx.x * 64;
  const int fr = lane & 15, fq = lane >> 4;
  const int rowA = tid >> 2, chA = (tid & 3) * 8;

  // ---------- phase 1: 64x256, K=128 ----------
  {
    const int wr = w * 16;
    const __bf16* Ab = A + (size_t)(bm + rowA) * 128 + chA;
    const __bf16* Bb = W1T + (size_t)rowA * 128 + chA;
    f32x4 acc[16] = {};
#define STG1(buf, k0)                                                 \
  do {                                                                \
    gload_lds16(Ab + (k0), &As[buf][rowA][chA]);                      \
    _Pragma("unroll") for (int r = 0; r < 4; ++r)                     \
        gload_lds16(Bb + (size_t)(r * 64) * 128 + (k0),               \
                    &Bs1[buf][rowA + r * 64][chA]);                   \
  } while (0)
    STG1(0, 0);
    __syncthreads();
    int cur = 0;
    for (int k0 = 0; k0 < 128; k0 += 32) {
      if (k0 + 32 < 128) STG1(cur ^ 1, k0 + 32);
      bf16x8 af = *(const bf16x8*)&As[cur][wr + fr][fq * 8];
#pragma unroll
      for (int n = 0; n < 16; ++n) {
        bf16x8 bq = *(const bf16x8*)&Bs1[cur][n * 16 + fr][fq * 8];
        acc[n] = __builtin_amdgcn_mfma_f32_16x16x32_bf16(af, bq, acc[n], 0, 0, 0);
      }
      __syncthreads();
      cur ^= 1;
    }
#undef STG1
    float cb[16], gv[16], bev[16];
#pragma unroll
    for (int n = 0; n < 16; ++n) {
      int col = n * 16 + fr;
      cb[n] = b1[col]; gv[n] = g1[col]; bev[n] = be1[col];
    }
#pragma unroll
    for (int j = 0; j < 4; ++j) {
      float cj[16], s = 0.f, s2 = 0.f;
#pragma unroll
      for (int n = 0; n < 16; ++n) {
        float c = acc[n][j] + cb[n];
        cj[n] = c; s += c; s2 += c * c;
      }
      s = red16(s); s2 = red16(s2);
      float mu = s * (1.f / 256);
      float var = fmaxf(s2 * (1.f / 256) - mu * mu, 0.f);
      float rr = rsqrtf(var + 1e-5f);
      int r = wr + fq * 4 + j;
#pragma unroll
      for (int n = 0; n < 16; ++n) {
        float y = (cj[n] - mu) * rr * gv[n] + bev[n];
        h1[r][n * 16 + fr] = (__bf16)fmaxf(y, 0.f);
      }
    }
  }
  __syncthreads();

  // ---------- phase 2: 64x128, K=256, A from h1 (LDS) ----------
  {
    const int wr = (w >> 1) * 32, wc = (w & 1) * 64;
    const __bf16* Bb = W2T + (size_t)rowA * 256 + chA;
    const __bf16* Bb2 = Bb + (size_t)64 * 256;
    f32x4 acc[2][4] = {};
#define STG2(buf, k0)                                   \
  do {                                                  \
    gload_lds16(Bb + (k0), &Bs2[buf][rowA][chA]);       \
    gload_lds16(Bb2 + (k0), &Bs2[buf][rowA + 64][chA]); \
  } while (0)
    STG2(0, 0);
    __syncthreads();
    int cur = 0;
    for (int k0 = 0; k0 < 256; k0 += 32) {
      if (k0 + 32 < 256) STG2(cur ^ 1, k0 + 32);
      bf16x8 af[2], bq[4];
#pragma unroll
      for (int m = 0; m < 2; ++m)
        af[m] = *(const bf16x8*)&h1[wr + m * 16 + fr][k0 + fq * 8];
#pragma unroll
      for (int n = 0; n < 4; ++n)
        bq[n] = *(const bf16x8*)&Bs2[cur][wc + n * 16 + fr][fq * 8];
#pragma unroll
      for (int m = 0; m < 2; ++m)
#pragma unroll
        for (int n = 0; n < 4; ++n)
          acc[m][n] =
              __builtin_amdgcn_mfma_f32_16x16x32_bf16(af[m], bq[n], acc[m][n], 0, 0, 0);
      __syncthreads();
      cur ^= 1;
    }
#undef STG2

    float cv[2][4][4];
#pragma unroll
    for (int m = 0; m < 2; ++m) {
      int r0 = wr + m * 16 + fq * 4;
#pragma unroll
      for (int j = 0; j < 4; ++j) {
        int gm = bm + r0 + j;
        float s = 0.f, s2 = 0.f;
#pragma unroll
        for (int n = 0; n < 4; ++n) {
          float c = acc[m][n][j] + b2[wc + n * 16 + fr];
          if (MODE != 0) c += xres[(size_t)gm * 128 + wc + n * 16 + fr];
          cv[m][n][j] = c;
          s += c; s2 += c * c;
        }
        s = red16(s); s2 = red16(s2);
        if (fr == 0) {
          redS[r0 + j][w & 1] = s;
          redS2[r0 + j][w & 1] = s2;
        }
      }
    }
    __syncthreads();
#pragma unroll
    for (int m = 0; m < 2; ++m) {
      int r0 = wr + m * 16 + fq * 4;
#pragma unroll
      for (int j = 0; j < 4; ++j) {
        int r = r0 + j;
        int gm = bm + r;
        float S = redS[r][0] + redS[r][1];
        float S2 = redS2[r][0] + redS2[r][1];
        float mu = S * (1.f / 128);
        float var = fmaxf(S2 * (1.f / 128) - mu * mu, 0.f);
        float rr = rsqrtf(var + 1e-5f);
        if constexpr (MODE < 2) {
          float* xp = xres + (size_t)gm * 128;
          __bf16* hp = (__bf16*)lnout + (size_t)gm * 128;
#pragma unroll
          for (int n = 0; n < 4; ++n) {
            int col = wc + n * 16 + fr;
            float c = cv[m][n][j];
            xp[col] = c;
            float y = (c - mu) * rr * dgv[col] + dbv[col];
            hp[col] = (__bf16)fmaxf(y, 0.f);
          }
        } else {
          int half = gm >= MP;
          int node = gm - half * MP;
          if (node < NN) {
            float* ep = (float*)lnout + (size_t)node * 256 + half * 128;
#pragma unroll
            for (int n = 0; n < 4; ++n) {
              int col = wc + n * 16 + fr;
              float y = (cv[m][n][j] - mu) * rr * dgv[col] + dbv[col];
              ep[col] = fmaxf(y, 0.f);
            }
          }
        }
      }
    }
  }
}

// ---------------- prologue: weight transpose-convert + degree count --------
struct WtDesc { const float* src; __bf16* dst; int K, N, Kpad, gbase; };
struct WtDescs { WtDesc d[10]; };
#define WTG 50176    // sum(N*Kpad)/8
#define CTG 80000    // 2*EE / 8

__global__ __launch_bounds__(256) void prep_kernel(
    WtDescs descs, const int* __restrict__ edge_index, int* __restrict__ deg,
    float* __restrict__ gp_sum) {
  const int tid = threadIdx.x;
  if (blockIdx.x == 0) gp_sum[tid] = 0.f;
  int g = blockIdx.x * 256 + tid;
  if (g >= WTG + CTG) return;
  if (g < WTG) {
    int wb = g;
    int di = 0;
#pragma unroll
    for (int t = 1; t < 10; ++t)
      if (wb >= descs.d[t].gbase) di = t;
    WtDesc de = descs.d[di];
    int local = wb - de.gbase;
    int kg8 = de.Kpad >> 3;
    int n = local / kg8, k0 = (local - n * kg8) * 8;
    bf16x8 o;
#pragma unroll
    for (int i = 0; i < 8; ++i) {
      int k = k0 + i;
      o[i] = (__bf16)((k < de.K) ? de.src[(size_t)k * de.N + n] : 0.f);
    }
    *(bf16x8*)(de.dst + (size_t)n * de.Kpad + k0) = o;
  } else {
    int i0 = (g - WTG) * 8;
    int ti = (i0 >= EE) ? 1 : 0;
    int e0 = i0 - ti * EE;
    int dst8[8];
    __builtin_memcpy(dst8, edge_index + (size_t)ti * 2 * EE + EE + e0, 32);
    int* dbase = deg + ti * NN;
#pragma unroll
    for (int j = 0; j < 8; ++j) atomicAdd(&dbase[dst8[j]], 1);
  }
}

// ---------------- CSR scan (block per ti) ----------------
__global__ __launch_bounds__(1024) void scan2_kernel(
    const int* __restrict__ deg_all, int* __restrict__ rowptr,
    int* __restrict__ cursor) {
  const int ti = blockIdx.x;
  const int* deg = deg_all + ti * NN;
  __shared__ int sums[1024];
  int tid = threadIdx.x;
  int chunk = (NN + 1023) / 1024;
  int begin = tid * chunk, end = min(begin + chunk, NN);
  int s = 0;
  for (int i = begin; i < end; ++i) s += deg[i];
  sums[tid] = s;
  __syncthreads();
  for (int off = 1; off < 1024; off <<= 1) {
    int v = (tid >= off) ? sums[tid - off] : 0;
    __syncthreads();
    sums[tid] += v;
    __syncthreads();
  }
  int running = ti * EE + sums[tid] - s;
  for (int i = begin; i < end; ++i) {
    rowptr[ti * NN + i] = running;
    cursor[ti * NN + i] = running;
    running += deg[i];
  }
  if (tid == 0 && ti == 1) rowptr[2 * NN] = 2 * EE;
}

// ---------------- GENConv softmax aggregation + residual -------------------
// 4 nodes/wave (quarter-wave per node), serial edge walk with 4-edge unroll.
// Edge4 4B records; 1/16 dequant folded into pre-scaled weights.
__global__ __launch_bounds__(256) void agg_kernel(
    const __bf16* __restrict__ xin, const int* __restrict__ rowptr,
    const Edge4* __restrict__ edges, const float* __restrict__ Wee,
    const float* __restrict__ bee, const float* __restrict__ tptr, int layer,
    __bf16* __restrict__ out) {
  int wave = threadIdx.x >> 6, lane = threadIdx.x & 63;
  int b = blockIdx.x;  // 625 * 8 blocks
  int x8 = b & 7;
  int q = x8 >> 1;
  int par = x8 & 1;
  int ti = q >> 1, chh = q & 1;
  int group = (b >> 3) * 2 + par;
  int qq = lane >> 4, c15 = lane & 15;
  int node = group * 16 + wave * 4 + qq;
  int gnode = ti * NN + node;
  int xrow = ti * MP + node;
  float t2 = tptr[layer] * 1.4426950408889634f;
  int c0 = chh * 64 + c15 * 4;
  float den[4] = {}, num[4] = {};
  int e = rowptr[gnode];
  const int e1 = rowptr[gnode + 1];

  if (t2 > 0.f) {
    float w0p[4], w1p[4], bvp[4];
#pragma unroll
    for (int i = 0; i < 4; ++i) {
      w0p[i] = Wee[c0 + i] * t2 * 0.0625f;   // fold 1/16 dequant
      w1p[i] = Wee[HH + c0 + i] * t2 * 0.0625f;
      bvp[i] = bee[c0 + i] * t2;
    }
#define MLPF(XV, ED)                                                      \
  do {                                                                    \
    float eax = (float)(ED).q0, eay = (float)(ED).q1;                     \
    _Pragma("unroll") for (int i = 0; i < 4; ++i) {                       \
      float te = fmaf(eax, w0p[i], fmaf(eay, w1p[i], bvp[i]));            \
      float sm = fmaxf(fmaf((float)(XV)[i], t2, te), 0.f);                \
      float ex = fexp2(sm);                                               \
      den[i] += ex; num[i] = fmaf(sm, ex, num[i]);                        \
    }                                                                     \
  } while (0)
    for (; e + 4 <= e1; e += 4) {
      Edge4 E0 = edges[e], E1 = edges[e + 1];
      Edge4 E2 = edges[e + 2], E3 = edges[e + 3];
      bf16x4 x0 = *(const bf16x4*)(xin + (size_t)E0.src * HH + c0);
      bf16x4 x1 = *(const bf16x4*)(xin + (size_t)E1.src * HH + c0);
      bf16x4 x2 = *(const bf16x4*)(xin + (size_t)E2.src * HH + c0);
      bf16x4 x3 = *(const bf16x4*)(xin + (size_t)E3.src * HH + c0);
      MLPF(x0, E0); MLPF(x1, E1); MLPF(x2, E2); MLPF(x3, E3);
    }
    for (; e < e1; ++e) {
      Edge4 E0 = edges[e];
      bf16x4 x0 = *(const bf16x4*)(xin + (size_t)E0.src * HH + c0);
      MLPF(x0, E0);
    }
#undef MLPF
    bf16x4 xr = *(const bf16x4*)(xin + (size_t)xrow * HH + c0);
    bf16x4 o;
#pragma unroll
    for (int i = 0; i < 4; ++i)
      o[i] = (__bf16)(num[i] / (t2 * (den[i] + 1e-16f)) + (float)xr[i]);
    *(bf16x4*)(out + (size_t)xrow * HH + c0) = o;
  } else {
    float w0[4], w1[4], bv[4];
#pragma unroll
    for (int i = 0; i < 4; ++i) {
      w0[i] = Wee[c0 + i] * 0.0625f;
      w1[i] = Wee[HH + c0 + i] * 0.0625f;
      bv[i] = bee[c0 + i];
    }
    for (; e < e1; ++e) {
      Edge4 E0 = edges[e];
      bf16x4 xv = *(const bf16x4*)(xin + (size_t)E0.src * HH + c0);
      float eax = (float)E0.q0, eay = (float)E0.q1;
#pragma unroll
      for (int i = 0; i < 4; ++i) {
        float m =
            fmaxf((float)xv[i] + eax * w0[i] + eay * w1[i] + bv[i], 0.f) + 1e-7f;
        float ex = fexp2(m * t2);
        den[i] += ex; num[i] += m * ex;
      }
    }
    bf16x4 xr = *(const bf16x4*)(xin + (size_t)xrow * HH + c0);
    bf16x4 o;
#pragma unroll
    for (int i = 0; i < 4; ++i)
      o[i] = (__bf16)(num[i] / (den[i] + 1e-16f) + (float)xr[i]);
    *(bf16x4*)(out + (size_t)xrow * HH + c0) = o;
  }
}

// ---------------- fused attention + node head (+ graph partials) -----------
__global__ __launch_bounds__(256) void attn_head_kernel(
    const float* __restrict__ emb, const float* __restrict__ Wq_n,
    const float* __restrict__ Wk_n, const float* __restrict__ Wv_n,
    const float* __restrict__ gn, const float* __restrict__ Wq_g,
    const float* __restrict__ Wk_g, const float* __restrict__ Wv_g,
    const float* __restrict__ gg, const __bf16* __restrict__ WTn1,
    const float* __restrict__ bn1, const float* __restrict__ Wn2,
    const float* __restrict__ b2h, float* __restrict__ outf,
    float* __restrict__ partial) {
  __shared__ __bf16 h1[64][264];
  __shared__ __bf16 Bs[2][256][32];
  __shared__ float gsum[4][256];
  const int tid = threadIdx.x;
  const int lane = tid & 63, wave = tid >> 6;
  const int bm = blockIdx.x * 64;
  const int c0 = lane * 2;
  float ag0 = 0.f, ag1 = 0.f, ag2 = 0.f, ag3 = 0.f;

#define ATTN_BODY(Wq, Wk, Wv, GAM, O0A, O0B, O1A, O1B)                        \
  {                                                                           \
    float gamma = *(GAM);                                                     \
    float wq00 = Wq[0], wq01 = Wq[1], wq10 = Wq[2], wq11 = Wq[3];             \
    float wk00 = Wk[0], wk01 = Wk[1], wk10 = Wk[2], wk11 = Wk[3];             \
    float wv00 = Wv[0], wv01 = Wv[1], wv10 = Wv[2], wv11 = Wv[3];             \
    float q0a = wq00 * x0.x + wq01 * x1.x, q0b = wq00 * x0.y + wq01 * x1.y;   \
    float q1a = wq10 * x0.x + wq11 * x1.x, q1b = wq10 * x0.y + wq11 * x1.y;   \
    float k0a = wk00 * x0.x + wk01 * x1.x, k0b = wk00 * x0.y + wk01 * x1.y;   \
    float k1a = wk10 * x0.x + wk11 * x1.x, k1b = wk10 * x0.y + wk11 * x1.y;   \
    float v0a = wv00 * x0.x + wv01 * x1.x, v0b = wv00 * x0.y + wv01 * x1.y;   \
    float v1a = wv10 * x0.x + wv11 * x1.x, v1b = wv10 * x0.y + wv11 * x1.y;   \
    float s00 = wave_sum(q0a * k0a + q0b * k0b);                              \
    float s01 = wave_sum(q0a * k1a + q0b * k1b);                              \
    float s10 = wave_sum(q1a * k0a + q1b * k0b);                              \
    float s11 = wave_sum(q1a * k1a + q1b * k1b);                              \
    float m0 = fmaxf(s00, s01);                                               \
    float e00 = __expf(s00 - m0), e01 = __expf(s01 - m0);                     \
    float i0 = 1.f / (e00 + e01);                                             \
    float a00 = e00 * i0, a01 = e01 * i0;                                     \
    float m1 = fmaxf(s10, s11);                                               \
    float e10 = __expf(s10 - m1), e11 = __expf(s11 - m1);                     \
    float i1 = 1.f / (e10 + e11);                                             \
    float a10 = e10 * i1, a11 = e11 * i1;                                     \
    O0A = gamma * (a00 * v0a + a01 * v1a) + x0.x;                             \
    O0B = gamma * (a00 * v0b + a01 * v1b) + x0.y;                             \
    O1A = gamma * (a10 * v0a + a11 * v1a) + x1.x;                             \
    O1B = gamma * (a10 * v0b + a11 * v1b) + x1.y;                             \
  }

  for (int i = wave; i < 64; i += 4) {
    int n = bm + i;
    if (n < NN) {
      const float* base = emb + (size_t)n * 256;
      float2 x0 = *(const float2*)(base + c0);
      float2 x1 = *(const float2*)(base + 128 + c0);
      float n0a, n0b, n1a, n1b;
      ATTN_BODY(Wq_n, Wk_n, Wv_n, gn, n0a, n0b, n1a, n1b);
      h1[i][c0] = (__bf16)n0a;
      h1[i][c0 + 1] = (__bf16)n0b;
      h1[i][128 + c0] = (__bf16)n1a;
      h1[i][129 + c0] = (__bf16)n1b;
      float g0a, g0b, g1a, g1b;
      ATTN_BODY(Wq_g, Wk_g, Wv_g, gg, g0a, g0b, g1a, g1b);
      ag0 += g0a; ag1 += g0b; ag2 += g1a; ag3 += g1b;
    } else {
      h1[i][c0] = (__bf16)0.f;
      h1[i][c0 + 1] = (__bf16)0.f;
      h1[i][128 + c0] = (__bf16)0.f;
      h1[i][129 + c0] = (__bf16)0.f;
    }
  }
#undef ATTN_BODY
  gsum[wave][c0] = ag0;
  gsum[wave][c0 + 1] = ag1;
  gsum[wave][128 + c0] = ag2;
  gsum[wave][129 + c0] = ag3;
  __syncthreads();
  partial[(size_t)blockIdx.x * 256 + tid] =
      gsum[0][tid] + gsum[1][tid] + gsum[2][tid] + gsum[3][tid];

  // ---------- phase B: head GEMM 64x256, K=256, A from h1 ----------
  const int fr = lane & 15, fq = lane >> 4;
  const int wr = wave * 16;
  const int rowA = tid >> 2, chA = (tid & 3) * 8;
  const __bf16* Bb = WTn1 + (size_t)rowA * 256 + chA;
  f32x4 acc[16] = {};
#define STGH(buf, k0)                                                \
  do {                                                               \
    _Pragma("unroll") for (int r = 0; r < 4; ++r)                    \
        gload_lds16(Bb + (size_t)(r * 64) * 256 + (k0),              \
                    &Bs[buf][rowA + r * 64][chA]);                   \
  } while (0)
  STGH(0, 0);
  __syncthreads();
  int cur = 0;
  for (int k0 = 0; k0 < 256; k0 += 32) {
    if (k0 + 32 < 256) STGH(cur ^ 1, k0 + 32);
    bf16x8 af = *(const bf16x8*)&h1[wr + fr][k0 + fq * 8];
#pragma unroll
    for (int n = 0; n < 16; ++n) {
      bf16x8 bq = *(const bf16x8*)&Bs[cur][n * 16 + fr][fq * 8];
      acc[n] = __builtin_amdgcn_mfma_f32_16x16x32_bf16(af, bq, acc[n], 0, 0, 0);
    }
    __syncthreads();
    cur ^= 1;
  }
#undef STGH
  float cb[16], w0[16], w1[16], w2[16];
#pragma unroll
  for (int n = 0; n < 16; ++n) {
    int col = n * 16 + fr;
    cb[n] = bn1[col];
    w0[n] = Wn2[col * 3 + 0];
    w1[n] = Wn2[col * 3 + 1];
    w2[n] = Wn2[col * 3 + 2];
  }
#pragma unroll
  for (int j = 0; j < 4; ++j) {
    float p0 = 0.f, p1 = 0.f, p2 = 0.f;
#pragma unroll
    for (int n = 0; n < 16; ++n) {
      float h = fmaxf(acc[n][j] + cb[n], 0.f);
      p0 += h * w0[n]; p1 += h * w1[n]; p2 += h * w2[n];
    }
    p0 = red16(p0); p1 = red16(p1); p2 = red16(p2);
    int gm = bm + wr + fq * 4 + j;
    if (fr == 0 && gm < NN) {
      float l0 = p0 + b2h[0], l1 = p1 + b2h[1], l2 = p2 + b2h[2];
      float m = fmaxf(l0, fmaxf(l1, l2));
      float lse = m + logf(__expf(l0 - m) + __expf(l1 - m) + __expf(l2 - m));
      outf[(size_t)gm * 3 + 0] = l0 - lse;
      outf[(size_t)gm * 3 + 1] = l1 - lse;
      outf[(size_t)gm * 3 + 2] = l2 - lse;
    }
  }
}

// ---------------- pool over per-block partials ----------------
__global__ __launch_bounds__(256) void pool_kernel(const float* __restrict__ partial,
                                                   float* __restrict__ gp_sum,
                                                   int nRows) {
  int c = threadIdx.x;
  float s = 0.f;
  for (int r = blockIdx.x; r < nRows; r += gridDim.x)
    s += partial[(size_t)r * 256 + c];
  atomicAdd(&gp_sum[c], s);
}

// ---------------- graph head (single block) ----------------
__global__ __launch_bounds__(256) void graph_head_kernel(
    const float* __restrict__ gp_sum, const float* __restrict__ Wg1,
    const float* __restrict__ bg1, const float* __restrict__ Wg2,
    const float* __restrict__ bg2, float* __restrict__ outp, float invN) {
  __shared__ float gp[256];
  __shared__ float h1[256];
  __shared__ float lg[2];
  int tid = threadIdx.x;
  gp[tid] = gp_sum[tid] * invN;
  __syncthreads();
  float acc = bg1[tid];
  for (int k = 0; k < 256; ++k) acc += gp[k] * Wg1[k * 256 + tid];
  h1[tid] = fmaxf(acc, 0.f);
  __syncthreads();
  if (tid < 2) {
    float l = bg2[tid];
    for (int c = 0; c < 256; ++c) l += h1[c] * Wg2[c * 2 + tid];
    lg[tid] = l;
  }
  __syncthreads();
  if (tid == 0) {
    float m = fmaxf(lg[0], lg[1]);
    float lse = m + logf(__expf(lg[0] - m) + __expf(lg[1] - m));
    outp[0] = lg[0] - lse;
    outp[1] = lg[1] - lse;
  }
}

// ---------------- launch ----------------
extern "C" void kernel_launch(void* const* d_in, const int* in_sizes, int n_in,
                              void* d_out, int out_size, void* d_ws, size_t ws_size,
                              hipStream_t stream) {
  (void)in_sizes; (void)n_in; (void)out_size; (void)ws_size;
  const float* node_feature = (const float*)d_in[0];
  const int* edge_index = (const int*)d_in[1];
  const float* edge_attr = (const float*)d_in[2];
  const float* Wne = (const float*)d_in[3];
  const float* bne = (const float*)d_in[4];
  const float* Wee = (const float*)d_in[5];
  const float* bee = (const float*)d_in[6];
  const float* W1 = (const float*)d_in[7];
  const float* b1 = (const float*)d_in[8];
  const float* g1 = (const float*)d_in[9];
  const float* be1 = (const float*)d_in[10];
  const float* W2 = (const float*)d_in[11];
  const float* b2 = (const float*)d_in[12];
  const float* dg = (const float*)d_in[13];
  const float* db = (const float*)d_in[14];
  const float* tpar = (const float*)d_in[15];
  const float* Wq_n = (const float*)d_in[16];
  const float* Wk_n = (const float*)d_in[17];
  const float* Wv_n = (const float*)d_in[18];
  const float* gamma_n = (const float*)d_in[19];
  const float* Wn1 = (const float*)d_in[20];
  const float* bn1 = (const float*)d_in[21];
  const float* Wn2 = (const float*)d_in[22];
  const float* bn2 = (const float*)d_in[23];
  const float* Wq_g = (const float*)d_in[24];
  const float* Wk_g = (const float*)d_in[25];
  const float* Wv_g = (const float*)d_in[26];
  const float* gamma_g = (const float*)d_in[27];
  const float* Wg1 = (const float*)d_in[28];
  const float* bg1 = (const float*)d_in[29];
  const float* Wg2 = (const float*)d_in[30];
  const float* bg2 = (const float*)d_in[31];
  float* out = (float*)d_out;

  // ---- workspace carve-out (256B-aligned regions) ----
  char* pc = (char*)d_ws;
  auto alloc = [&](size_t bytes) {
    char* r = pc;
    pc += (bytes + 255) & ~(size_t)255;
    return r;
  };
  float* xbuf = (float*)alloc((size_t)2 * MP * HH * 4);       // f32 residual
  __bf16* hbuf_b = (__bf16*)alloc((size_t)2 * MP * HH * 2);   // LN'd agg input
  float* emb = (float*)alloc((size_t)NN * 2 * HH * 4);        // [N,T,H] f32
  __bf16* aggout_b = (__bf16*)alloc((size_t)2 * MP * HH * 2); // agg out
  float* partial = xbuf;        // alias: graph-attn partials [314][256]
  __bf16* wt_ne = (__bf16*)alloc((size_t)128 * 576 * 2);
  __bf16* wt1 = (__bf16*)alloc((size_t)4 * 256 * 128 * 2);
  __bf16* wt2 = (__bf16*)alloc((size_t)4 * 128 * 256 * 2);
  __bf16* wtn1 = (__bf16*)alloc((size_t)256 * 256 * 2);
  float* gp_sum = (float*)alloc(256 * 4);
  int* deg = (int*)alloc((size_t)2 * NN * 4);
  int* cursor = (int*)alloc((size_t)2 * NN * 4);
  int* rowptr = (int*)alloc((size_t)(2 * NN + 2) * 4);
  Edge4* edges = (Edge4*)alloc((size_t)2 * EE * 4);

  const int gRows2 = 2 * MP / 64;  // 628 row-blocks, stacked layer kernel

  WtDescs wd;
  int gb = 0;
  wd.d[0] = {Wne, wt_ne, FF, HH, 576, gb}; gb += HH * 576 / 8;
  for (int l = 0; l < 4; ++l) {
    wd.d[1 + l] = {W1 + (size_t)l * HH * 256, wt1 + (size_t)l * 256 * HH, HH, 256,
                   HH, gb};
    gb += 256 * HH / 8;
  }
  for (int l = 0; l < 4; ++l) {
    wd.d[5 + l] = {W2 + (size_t)l * 256 * HH, wt2 + (size_t)l * HH * 256, 256, HH,
                   256, gb};
    gb += HH * 256 / 8;
  }
  wd.d[9] = {Wn1, wtn1, 256, 256, 256, gb};

  // prologue: deg zero; weight converts + degree count + gp_sum zero
  hipMemsetAsync(deg, 0, 2 * NN * sizeof(int), stream);
  prep_kernel<<<(WTG + CTG + 255) / 256, 256, 0, stream>>>(wd, edge_index, deg,
                                                           gp_sum);
  scan2_kernel<<<2, 1024, 0, stream>>>(deg, rowptr, cursor);
  // encoder GEMM (f32 A async+swizzled, dup) + XCD-routed edge scatter
  enc_scatter_kernel<<<ENCB + 8 * SSB, 256, 0, stream>>>(
      node_feature, wt_ne, bne, hbuf_b, edge_index, edge_attr, cursor, edges);

  // layer loop, both ti at once: agg + fused MLP (lin1+LN+relu | lin2+res+LN)
  for (int l = 0; l < LL; ++l) {
    agg_kernel<<<625 * 8, 256, 0, stream>>>(hbuf_b, rowptr, edges, Wee, bee, tpar,
                                            l, aggout_b);
    const __bf16* w1l = wt1 + (size_t)l * 256 * HH;
    const __bf16* w2l = wt2 + (size_t)l * HH * 256;
    if (l == 0)
      gemm_layer<0><<<gRows2, 256, 0, stream>>>(
          aggout_b, w1l, b1 + l * 2 * HH, g1 + l * 2 * HH, be1 + l * 2 * HH, w2l,
          b2 + l * HH, xbuf, dg + 1 * HH, db + 1 * HH, hbuf_b);
    else if (l < LL - 1)
      gemm_layer<1><<<gRows2, 256, 0, stream>>>(
          aggout_b, w1l, b1 + l * 2 * HH, g1 + l * 2 * HH, be1 + l * 2 * HH, w2l,
          b2 + l * HH, xbuf, dg + (l + 1) * HH, db + (l + 1) * HH, hbuf_b);
    else
      gemm_layer<2><<<gRows2, 256, 0, stream>>>(
          aggout_b, w1l, b1 + l * 2 * HH, g1 + l * 2 * HH, be1 + l * 2 * HH, w2l,
          b2 + l * HH, xbuf, dg, db, emb);
  }

  // fused attention + node head (+ graph partials in one pass)
  attn_head_kernel<<<MP / 64, 256, 0, stream>>>(
      emb, Wq_n, Wk_n, Wv_n, gamma_n, Wq_g, Wk_g, Wv_g, gamma_g, wtn1, bn1, Wn2,
      bn2, out, partial);
  // graph head
  pool_kernel<<<128, 256, 0, stream>>>(partial, gp_sum, MP / 64);
  graph_head_kernel<<<1, 256, 0, stream>>>(gp_sum, Wg1, bg1, Wg2, bg2,
                                           out + (size_t)NN * CN, 1.0f / NN);
}

// Round 17
// 411.774 us; speedup vs baseline: 1.0302x; 1.0302x over previous
//
#include <hip/hip_runtime.h>

#define NN 20000
#define TT 2
#define HH 128
#define LL 4
#define EE 320000
#define FF 514
#define CN 3
#define CG 2
#define MP 20096  // rows per ti-half, padded to multiple of 128

typedef __bf16 bf16x8 __attribute__((ext_vector_type(8)));
typedef __bf16 bf16x4 __attribute__((ext_vector_type(4)));
typedef __bf16 bf16x2 __attribute__((ext_vector_type(2)));
typedef float f32x4 __attribute__((ext_vector_type(4)));

struct __align__(8) Edge { int src; __bf16 ea0, ea1; };

// ---------------- wave helpers ----------------
__device__ inline float wave_sum(float v) {
#pragma unroll
  for (int off = 32; off; off >>= 1) v += __shfl_xor(v, off);
  return v;
}
__device__ inline float red16(float v) {  // reduce across fr = lane&15
  v += __shfl_xor(v, 1); v += __shfl_xor(v, 2);
  v += __shfl_xor(v, 4); v += __shfl_xor(v, 8);
  return v;
}

__device__ __forceinline__ float fexp2(float x) {
#if __has_builtin(__builtin_amdgcn_exp2f)
  return __builtin_amdgcn_exp2f(x);
#else
  return exp2f(x);
#endif
}

__device__ __forceinline__ void gload_lds16(const void* g, void* l) {
  __builtin_amdgcn_global_load_lds(
      (const __attribute__((address_space(1))) unsigned int*)g,
      (__attribute__((address_space(3))) unsigned int*)l, 16, 0, 0);
}

// ---------------- fused encoder GEMM (f32 A direct) + XCD-routed scatter ----
#define ENCB (MP / 64)
#define SSB 313   // ceil(2*EE / (256*8))
#define CHUNK 5000  // 2*NN/8 gnodes per XCD chunk
__global__ __launch_bounds__(256) void enc_scatter_kernel(
    const float* __restrict__ Af, const __bf16* __restrict__ BT,
    const float* __restrict__ bias, __bf16* __restrict__ C,
    const int* __restrict__ edge_index, const float* __restrict__ edge_attr,
    int* __restrict__ cursor, Edge* __restrict__ edges) {
  __shared__ __bf16 As[2][64][32];
  __shared__ __bf16 Bs[2][128][32];
  const int tid = threadIdx.x;
  if (blockIdx.x >= ENCB) {
    int sb = blockIdx.x - ENCB;
    int chunk = sb & 7;
    int slice = sb >> 3;
    int i0 = slice * 2048 + tid * 8;
    if (i0 >= 2 * EE) return;
    int ti = (i0 >= EE) ? 1 : 0;
    int e0 = i0 - ti * EE;
    const int* srcp = edge_index + (size_t)ti * 2 * EE;
    int dst8[8];
    __builtin_memcpy(dst8, srcp + EE + e0, 32);
#pragma unroll
    for (int j = 0; j < 8; ++j) {
      int gnode = ti * NN + dst8[j];
      if (gnode / CHUNK != chunk) continue;
      int s = srcp[e0 + j];
      float2 ea = ((const float2*)edge_attr)[(size_t)ti * EE + e0 + j];
      int pos = atomicAdd(&cursor[gnode], 1);
      Edge ed;
      ed.src = s + ti * MP;
      ed.ea0 = (__bf16)ea.x; ed.ea1 = (__bf16)ea.y;
      __builtin_memcpy(&edges[pos], &ed, sizeof(Edge));
    }
    return;
  }
  const int K = 576;
  const int lane = tid & 63, w = tid >> 6;
  const int bm = blockIdx.x * 64;
  const int wr = (w >> 1) * 32, wc = (w & 1) * 64;
  const int fr = lane & 15, fq = lane >> 4;
  const int rowA = tid >> 2, chA = (tid & 3) * 8;
  const bool rowOK = (bm + rowA) < NN;
  const float* Arow = Af + (size_t)(bm + rowA) * FF;
  const __bf16* Bb = BT + (size_t)rowA * K + chA;
  const __bf16* Bb2 = Bb + (size_t)64 * K;
  f32x4 acc[2][4] = {};
  float va[8];

#define LOADA(k0)                                                   \
  do {                                                              \
    int c0_ = (k0) + chA;                                           \
    if (rowOK && c0_ + 8 <= FF) {                                   \
      __builtin_memcpy(va, Arow + c0_, 32);                         \
    } else {                                                        \
      _Pragma("unroll") for (int i_ = 0; i_ < 8; ++i_)              \
          va[i_] = (rowOK && c0_ + i_ < FF) ? Arow[c0_ + i_] : 0.f; \
    }                                                               \
  } while (0)
#define WRITEA(buf)                                                 \
  do {                                                              \
    bf16x8 o_;                                                      \
    _Pragma("unroll") for (int i_ = 0; i_ < 8; ++i_)                \
        o_[i_] = (__bf16)va[i_];                                    \
    *(bf16x8*)&As[buf][rowA][chA] = o_;                             \
  } while (0)
#define STAGEB(buf, k0)                                 \
  do {                                                  \
    gload_lds16(Bb + (k0), &Bs[buf][rowA][chA]);        \
    gload_lds16(Bb2 + (k0), &Bs[buf][rowA + 64][chA]);  \
  } while (0)

  LOADA(0); WRITEA(0);
  LOADA(32);  // prefetch next A tile into regs (consumed next iter)
  STAGEB(0, 0);
  __syncthreads();
  int cur = 0;
  for (int k0 = 0; k0 < K; k0 += 32) {
    bool last = (k0 + 32 >= K);
    if (!last) STAGEB(cur ^ 1, k0 + 32);
    bf16x8 af[2], bq[4];
#pragma unroll
    for (int m = 0; m < 2; ++m)
      af[m] = *(const bf16x8*)&As[cur][wr + m * 16 + fr][fq * 8];
#pragma unroll
    for (int n = 0; n < 4; ++n)
      bq[n] = *(const bf16x8*)&Bs[cur][wc + n * 16 + fr][fq * 8];
#pragma unroll
    for (int m = 0; m < 2; ++m)
#pragma unroll
      for (int n = 0; n < 4; ++n)
        acc[m][n] =
            __builtin_amdgcn_mfma_f32_16x16x32_bf16(af[m], bq[n], acc[m][n], 0, 0, 0);
    if (!last) {
      WRITEA(cur ^ 1);              // va holds k0+32 data (issued 1 iter ago)
      if (k0 + 64 < K) LOADA(k0 + 64);  // in flight across sync + next MFMA
    }
    __syncthreads();
    cur ^= 1;
  }
#undef LOADA
#undef WRITEA
#undef STAGEB
#pragma unroll
  for (int m = 0; m < 2; ++m) {
#pragma unroll
    for (int n = 0; n < 4; ++n) {
#pragma unroll
      for (int j = 0; j < 4; ++j) {
        int gm = bm + wr + m * 16 + fq * 4 + j;
        int gn = wc + n * 16 + fr;
        if (gm < NN) {
          __bf16 c = (__bf16)(acc[m][n][j] + bias[gn]);
          C[(size_t)gm * 128 + gn] = c;
          C[(size_t)(gm + MP) * 128 + gn] = c;
        }
      }
    }
  }
}

// ---------------- fused layer MLP: lin1+LN+relu (LDS) -> lin2+res+LN -------
template <int MODE>
__global__ __launch_bounds__(256) void gemm_layer(
    const __bf16* __restrict__ A, const __bf16* __restrict__ W1T,
    const float* __restrict__ b1, const float* __restrict__ g1,
    const float* __restrict__ be1, const __bf16* __restrict__ W2T,
    const float* __restrict__ b2, float* __restrict__ xres,
    const float* __restrict__ dgv, const float* __restrict__ dbv,
    void* __restrict__ lnout) {
  __shared__ char smem[40960];
  __shared__ __bf16 h1[64][264];
  __shared__ float redS[64][2], redS2[64][2];
  auto As = (__bf16(*)[64][32])smem;
  auto Bs1 = (__bf16(*)[256][32])(smem + 8192);
  auto Bs2 = (__bf16(*)[128][32])smem;
  const int tid = threadIdx.x;
  const int lane = tid & 63, w = tid >> 6;
  const int bm = blockIdx.x * 64;
  const int fr = lane & 15, fq = lane >> 4;
  const int rowA = tid >> 2, chA = (tid & 3) * 8;

  // ---------- phase 1: 64x256, K=128 ----------
  {
    const int wr = w * 16;
    const __bf16* Ab = A + (size_t)(bm + rowA) * 128 + chA;
    const __bf16* Bb = W1T + (size_t)rowA * 128 + chA;
    f32x4 acc[16] = {};
#define STG1(buf, k0)                                                 \
  do {                                                                \
    gload_lds16(Ab + (k0), &As[buf][rowA][chA]);                      \
    _Pragma("unroll") for (int r = 0; r < 4; ++r)                     \
        gload_lds16(Bb + (size_t)(r * 64) * 128 + (k0),               \
                    &Bs1[buf][rowA + r * 64][chA]);                   \
  } while (0)
    STG1(0, 0);
    __syncthreads();
    int cur = 0;
    for (int k0 = 0; k0 < 128; k0 += 32) {
      if (k0 + 32 < 128) STG1(cur ^ 1, k0 + 32);
      bf16x8 af = *(const bf16x8*)&As[cur][wr + fr][fq * 8];
#pragma unroll
      for (int n = 0; n < 16; ++n) {
        bf16x8 bq = *(const bf16x8*)&Bs1[cur][n * 16 + fr][fq * 8];
        acc[n] = __builtin_amdgcn_mfma_f32_16x16x32_bf16(af, bq, acc[n], 0, 0, 0);
      }
      __syncthreads();
      cur ^= 1;
    }
#undef STG1
    float cb[16], gv[16], bev[16];
#pragma unroll
    for (int n = 0; n < 16; ++n) {
      int col = n * 16 + fr;
      cb[n] = b1[col]; gv[n] = g1[col]; bev[n] = be1[col];
    }
#pragma unroll
    for (int j = 0; j < 4; ++j) {
      float cj[16], s = 0.f, s2 = 0.f;
#pragma unroll
      for (int n = 0; n < 16; ++n) {
        float c = acc[n][j] + cb[n];
        cj[n] = c; s += c; s2 += c * c;
      }
      s = red16(s); s2 = red16(s2);
      float mu = s * (1.f / 256);
      float var = fmaxf(s2 * (1.f / 256) - mu * mu, 0.f);
      float rr = rsqrtf(var + 1e-5f);
      int r = wr + fq * 4 + j;
#pragma unroll
      for (int n = 0; n < 16; ++n) {
        float y = (cj[n] - mu) * rr * gv[n] + bev[n];
        h1[r][n * 16 + fr] = (__bf16)fmaxf(y, 0.f);
      }
    }
  }
  __syncthreads();

  // ---------- phase 2: 64x128, K=256, A from h1 (LDS) ----------
  {
    const int wr = (w >> 1) * 32, wc = (w & 1) * 64;
    const __bf16* Bb = W2T + (size_t)rowA * 256 + chA;
    const __bf16* Bb2 = Bb + (size_t)64 * 256;
    f32x4 acc[2][4] = {};
#define STG2(buf, k0)                                   \
  do {                                                  \
    gload_lds16(Bb + (k0), &Bs2[buf][rowA][chA]);       \
    gload_lds16(Bb2 + (k0), &Bs2[buf][rowA + 64][chA]); \
  } while (0)
    STG2(0, 0);
    __syncthreads();
    int cur = 0;
    for (int k0 = 0; k0 < 256; k0 += 32) {
      if (k0 + 32 < 256) STG2(cur ^ 1, k0 + 32);
      bf16x8 af[2], bq[4];
#pragma unroll
      for (int m = 0; m < 2; ++m)
        af[m] = *(const bf16x8*)&h1[wr + m * 16 + fr][k0 + fq * 8];
#pragma unroll
      for (int n = 0; n < 4; ++n)
        bq[n] = *(const bf16x8*)&Bs2[cur][wc + n * 16 + fr][fq * 8];
#pragma unroll
      for (int m = 0; m < 2; ++m)
#pragma unroll
        for (int n = 0; n < 4; ++n)
          acc[m][n] =
              __builtin_amdgcn_mfma_f32_16x16x32_bf16(af[m], bq[n], acc[m][n], 0, 0, 0);
      __syncthreads();
      cur ^= 1;
    }
#undef STG2

    float cv[2][4][4];
#pragma unroll
    for (int m = 0; m < 2; ++m) {
      int r0 = wr + m * 16 + fq * 4;
#pragma unroll
      for (int j = 0; j < 4; ++j) {
        int gm = bm + r0 + j;
        float s = 0.f, s2 = 0.f;
#pragma unroll
        for (int n = 0; n < 4; ++n) {
          float c = acc[m][n][j] + b2[wc + n * 16 + fr];
          if (MODE != 0) c += xres[(size_t)gm * 128 + wc + n * 16 + fr];
          cv[m][n][j] = c;
          s += c; s2 += c * c;
        }
        s = red16(s); s2 = red16(s2);
        if (fr == 0) {
          redS[r0 + j][w & 1] = s;
          redS2[r0 + j][w & 1] = s2;
        }
      }
    }
    __syncthreads();
#pragma unroll
    for (int m = 0; m < 2; ++m) {
      int r0 = wr + m * 16 + fq * 4;
#pragma unroll
      for (int j = 0; j < 4; ++j) {
        int r = r0 + j;
        int gm = bm + r;
        float S = redS[r][0] + redS[r][1];
        float S2 = redS2[r][0] + redS2[r][1];
        float mu = S * (1.f / 128);
        float var = fmaxf(S2 * (1.f / 128) - mu * mu, 0.f);
        float rr = rsqrtf(var + 1e-5f);
        if constexpr (MODE < 2) {
          float* xp = xres + (size_t)gm * 128;
          __bf16* hp = (__bf16*)lnout + (size_t)gm * 128;
#pragma unroll
          for (int n = 0; n < 4; ++n) {
            int col = wc + n * 16 + fr;
            float c = cv[m][n][j];
            xp[col] = c;
            float y = (c - mu) * rr * dgv[col] + dbv[col];
            hp[col] = (__bf16)fmaxf(y, 0.f);
          }
        } else {
          int half = gm >= MP;
          int node = gm - half * MP;
          if (node < NN) {
            float* ep = (float*)lnout + (size_t)node * 256 + half * 128;
#pragma unroll
            for (int n = 0; n < 4; ++n) {
              int col = wc + n * 16 + fr;
              float y = (cv[m][n][j] - mu) * rr * dgv[col] + dbv[col];
              ep[col] = fmaxf(y, 0.f);
            }
          }
        }
      }
    }
  }
}

// ---------------- prologue: weight transpose-convert + degree count --------
struct WtDesc { const float* src; __bf16* dst; int K, N, Kpad, gbase; };
struct WtDescs { WtDesc d[10]; };
#define WTG 50176    // sum(N*Kpad)/8
#define CTG 80000    // 2*EE / 8

__global__ __launch_bounds__(256) void prep_kernel(
    WtDescs descs, const int* __restrict__ edge_index, int* __restrict__ deg,
    float* __restrict__ gp_sum) {
  const int tid = threadIdx.x;
  if (blockIdx.x == 0) gp_sum[tid] = 0.f;
  int g = blockIdx.x * 256 + tid;
  if (g >= WTG + CTG) return;
  if (g < WTG) {
    int wb = g;
    int di = 0;
#pragma unroll
    for (int t = 1; t < 10; ++t)
      if (wb >= descs.d[t].gbase) di = t;
    WtDesc de = descs.d[di];
    int local = wb - de.gbase;
    int kg8 = de.Kpad >> 3;
    int n = local / kg8, k0 = (local - n * kg8) * 8;
    bf16x8 o;
#pragma unroll
    for (int i = 0; i < 8; ++i) {
      int k = k0 + i;
      o[i] = (__bf16)((k < de.K) ? de.src[(size_t)k * de.N + n] : 0.f);
    }
    *(bf16x8*)(de.dst + (size_t)n * de.Kpad + k0) = o;
  } else {
    int i0 = (g - WTG) * 8;
    int ti = (i0 >= EE) ? 1 : 0;
    int e0 = i0 - ti * EE;
    int dst8[8];
    __builtin_memcpy(dst8, edge_index + (size_t)ti * 2 * EE + EE + e0, 32);
    int* dbase = deg + ti * NN;
#pragma unroll
    for (int j = 0; j < 8; ++j) atomicAdd(&dbase[dst8[j]], 1);
  }
}

// ---------------- CSR scan (block per ti) ----------------
__global__ __launch_bounds__(1024) void scan2_kernel(
    const int* __restrict__ deg_all, int* __restrict__ rowptr,
    int* __restrict__ cursor) {
  const int ti = blockIdx.x;
  const int* deg = deg_all + ti * NN;
  __shared__ int sums[1024];
  int tid = threadIdx.x;
  int chunk = (NN + 1023) / 1024;
  int begin = tid * chunk, end = min(begin + chunk, NN);
  int s = 0;
  for (int i = begin; i < end; ++i) s += deg[i];
  sums[tid] = s;
  __syncthreads();
  for (int off = 1; off < 1024; off <<= 1) {
    int v = (tid >= off) ? sums[tid - off] : 0;
    __syncthreads();
    sums[tid] += v;
    __syncthreads();
  }
  int running = ti * EE + sums[tid] - s;
  for (int i = begin; i < end; ++i) {
    rowptr[ti * NN + i] = running;
    cursor[ti * NN + i] = running;
    running += deg[i];
  }
  if (tid == 0 && ti == 1) rowptr[2 * NN] = 2 * EE;
}

// ---------------- GENConv softmax aggregation + residual -------------------
// 4 nodes/wave (quarter-wave per node), serial edge walk with 4-edge unroll
// (4 gathers in flight). Channels lane-owned. XCD quadrant pinning via b&7.
__global__ __launch_bounds__(256) void agg_kernel(
    const __bf16* __restrict__ xin, const int* __restrict__ rowptr,
    const Edge* __restrict__ edges, const float* __restrict__ Wee,
    const float* __restrict__ bee, const float* __restrict__ tptr, int layer,
    __bf16* __restrict__ out) {
  int wave = threadIdx.x >> 6, lane = threadIdx.x & 63;
  int b = blockIdx.x;  // 625 * 8 blocks
  int x8 = b & 7;
  int q = x8 >> 1;
  int par = x8 & 1;
  int ti = q >> 1, chh = q & 1;
  int group = (b >> 3) * 2 + par;
  int qq = lane >> 4, c15 = lane & 15;
  int node = group * 16 + wave * 4 + qq;
  int gnode = ti * NN + node;
  int xrow = ti * MP + node;
  float t2 = tptr[layer] * 1.4426950408889634f;
  int c0 = chh * 64 + c15 * 4;
  float den[4] = {}, num[4] = {};
  int e = rowptr[gnode];
  const int e1 = rowptr[gnode + 1];

  if (t2 > 0.f) {
    float w0p[4], w1p[4], bvp[4];
#pragma unroll
    for (int i = 0; i < 4; ++i) {
      w0p[i] = Wee[c0 + i] * t2;
      w1p[i] = Wee[HH + c0 + i] * t2;
      bvp[i] = bee[c0 + i] * t2;
    }
#define MLPF(XV, ED)                                                      \
  do {                                                                    \
    float eax = (float)(ED).ea0, eay = (float)(ED).ea1;                   \
    _Pragma("unroll") for (int i = 0; i < 4; ++i) {                       \
      float te = fmaf(eax, w0p[i], fmaf(eay, w1p[i], bvp[i]));            \
      float sm = fmaxf(fmaf((float)(XV)[i], t2, te), 0.f);                \
      float ex = fexp2(sm);                                               \
      den[i] += ex; num[i] = fmaf(sm, ex, num[i]);                        \
    }                                                                     \
  } while (0)
    for (; e + 4 <= e1; e += 4) {
      Edge E0 = edges[e], E1 = edges[e + 1];
      Edge E2 = edges[e + 2], E3 = edges[e + 3];
      bf16x4 x0 = *(const bf16x4*)(xin + (size_t)E0.src * HH + c0);
      bf16x4 x1 = *(const bf16x4*)(xin + (size_t)E1.src * HH + c0);
      bf16x4 x2 = *(const bf16x4*)(xin + (size_t)E2.src * HH + c0);
      bf16x4 x3 = *(const bf16x4*)(xin + (size_t)E3.src * HH + c0);
      MLPF(x0, E0); MLPF(x1, E1); MLPF(x2, E2); MLPF(x3, E3);
    }
    for (; e < e1; ++e) {
      Edge E0 = edges[e];
      bf16x4 x0 = *(const bf16x4*)(xin + (size_t)E0.src * HH + c0);
      MLPF(x0, E0);
    }
#undef MLPF
    bf16x4 xr = *(const bf16x4*)(xin + (size_t)xrow * HH + c0);
    bf16x4 o;
#pragma unroll
    for (int i = 0; i < 4; ++i)
      o[i] = (__bf16)(num[i] / (t2 * (den[i] + 1e-16f)) + (float)xr[i]);
    *(bf16x4*)(out + (size_t)xrow * HH + c0) = o;
  } else {
    float w0[4], w1[4], bv[4];
#pragma unroll
    for (int i = 0; i < 4; ++i) {
      w0[i] = Wee[c0 + i];
      w1[i] = Wee[HH + c0 + i];
      bv[i] = bee[c0 + i];
    }
    for (; e < e1; ++e) {
      Edge E0 = edges[e];
      bf16x4 xv = *(const bf16x4*)(xin + (size_t)E0.src * HH + c0);
      float eax = (float)E0.ea0, eay = (float)E0.ea1;
#pragma unroll
      for (int i = 0; i < 4; ++i) {
        float m =
            fmaxf((float)xv[i] + eax * w0[i] + eay * w1[i] + bv[i], 0.f) + 1e-7f;
        float ex = fexp2(m * t2);
        den[i] += ex; num[i] += m * ex;
      }
    }
    bf16x4 xr = *(const bf16x4*)(xin + (size_t)xrow * HH + c0);
    bf16x4 o;
#pragma unroll
    for (int i = 0; i < 4; ++i)
      o[i] = (__bf16)(num[i] / (den[i] + 1e-16f) + (float)xr[i]);
    *(bf16x4*)(out + (size_t)xrow * HH + c0) = o;
  }
}

// ---------------- fused attention + node head (+ graph partials) -----------
__global__ __launch_bounds__(256) void attn_head_kernel(
    const float* __restrict__ emb, const float* __restrict__ Wq_n,
    const float* __restrict__ Wk_n, const float* __restrict__ Wv_n,
    const float* __restrict__ gn, const float* __restrict__ Wq_g,
    const float* __restrict__ Wk_g, const float* __restrict__ Wv_g,
    const float* __restrict__ gg, const __bf16* __restrict__ WTn1,
    const float* __restrict__ bn1, const float* __restrict__ Wn2,
    const float* __restrict__ b2h, float* __restrict__ outf,
    float* __restrict__ partial) {
  __shared__ __bf16 h1[64][264];
  __shared__ __bf16 Bs[2][256][32];
  __shared__ float gsum[4][256];
  const int tid = threadIdx.x;
  const int lane = tid & 63, wave = tid >> 6;
  const int bm = blockIdx.x * 64;
  const int c0 = lane * 2;
  float ag0 = 0.f, ag1 = 0.f, ag2 = 0.f, ag3 = 0.f;

#define ATTN_BODY(Wq, Wk, Wv, GAM, O0A, O0B, O1A, O1B)                        \
  {                                                                           \
    float gamma = *(GAM);                                                     \
    float wq00 = Wq[0], wq01 = Wq[1], wq10 = Wq[2], wq11 = Wq[3];             \
    float wk00 = Wk[0], wk01 = Wk[1], wk10 = Wk[2], wk11 = Wk[3];             \
    float wv00 = Wv[0], wv01 = Wv[1], wv10 = Wv[2], wv11 = Wv[3];             \
    float q0a = wq00 * x0.x + wq01 * x1.x, q0b = wq00 * x0.y + wq01 * x1.y;   \
    float q1a = wq10 * x0.x + wq11 * x1.x, q1b = wq10 * x0.y + wq11 * x1.y;   \
    float k0a = wk00 * x0.x + wk01 * x1.x, k0b = wk00 * x0.y + wk01 * x1.y;   \
    float k1a = wk10 * x0.x + wk11 * x1.x, k1b = wk10 * x0.y + wk11 * x1.y;   \
    float v0a = wv00 * x0.x + wv01 * x1.x, v0b = wv00 * x0.y + wv01 * x1.y;   \
    float v1a = wv10 * x0.x + wv11 * x1.x, v1b = wv10 * x0.y + wv11 * x1.y;   \
    float s00 = wave_sum(q0a * k0a + q0b * k0b);                              \
    float s01 = wave_sum(q0a * k1a + q0b * k1b);                              \
    float s10 = wave_sum(q1a * k0a + q1b * k0b);                              \
    float s11 = wave_sum(q1a * k1a + q1b * k1b);                              \
    float m0 = fmaxf(s00, s01);                                               \
    float e00 = __expf(s00 - m0), e01 = __expf(s01 - m0);                     \
    float i0 = 1.f / (e00 + e01);                                             \
    float a00 = e00 * i0, a01 = e01 * i0;                                     \
    float m1 = fmaxf(s10, s11);                                               \
    float e10 = __expf(s10 - m1), e11 = __expf(s11 - m1);                     \
    float i1 = 1.f / (e10 + e11);                                             \
    float a10 = e10 * i1, a11 = e11 * i1;                                     \
    O0A = gamma * (a00 * v0a + a01 * v1a) + x0.x;                             \
    O0B = gamma * (a00 * v0b + a01 * v1b) + x0.y;                             \
    O1A = gamma * (a10 * v0a + a11 * v1a) + x1.x;                             \
    O1B = gamma * (a10 * v0b + a11 * v1b) + x1.y;                             \
  }

  for (int i = wave; i < 64; i += 4) {
    int n = bm + i;
    if (n < NN) {
      const float* base = emb + (size_t)n * 256;
      float2 x0 = *(const float2*)(base + c0);
      float2 x1 = *(const float2*)(base + 128 + c0);
      float n0a, n0b, n1a, n1b;
      ATTN_BODY(Wq_n, Wk_n, Wv_n, gn, n0a, n0b, n1a, n1b);
      h1[i][c0] = (__bf16)n0a;
      h1[i][c0 + 1] = (__bf16)n0b;
      h1[i][128 + c0] = (__bf16)n1a;
      h1[i][129 + c0] = (__bf16)n1b;
      float g0a, g0b, g1a, g1b;
      ATTN_BODY(Wq_g, Wk_g, Wv_g, gg, g0a, g0b, g1a, g1b);
      ag0 += g0a; ag1 += g0b; ag2 += g1a; ag3 += g1b;
    } else {
      h1[i][c0] = (__bf16)0.f;
      h1[i][c0 + 1] = (__bf16)0.f;
      h1[i][128 + c0] = (__bf16)0.f;
      h1[i][129 + c0] = (__bf16)0.f;
    }
  }
#undef ATTN_BODY
  gsum[wave][c0] = ag0;
  gsum[wave][c0 + 1] = ag1;
  gsum[wave][128 + c0] = ag2;
  gsum[wave][129 + c0] = ag3;
  __syncthreads();
  partial[(size_t)blockIdx.x * 256 + tid] =
      gsum[0][tid] + gsum[1][tid] + gsum[2][tid] + gsum[3][tid];

  // ---------- phase B: head GEMM 64x256, K=256, A from h1 ----------
  const int fr = lane & 15, fq = lane >> 4;
  const int wr = wave * 16;
  const int rowA = tid >> 2, chA = (tid & 3) * 8;
  const __bf16* Bb = WTn1 + (size_t)rowA * 256 + chA;
  f32x4 acc[16] = {};
#define STGH(buf, k0)                                                \
  do {                                                               \
    _Pragma("unroll") for (int r = 0; r < 4; ++r)                    \
        gload_lds16(Bb + (size_t)(r * 64) * 256 + (k0),              \
                    &Bs[buf][rowA + r * 64][chA]);                   \
  } while (0)
  STGH(0, 0);
  __syncthreads();
  int cur = 0;
  for (int k0 = 0; k0 < 256; k0 += 32) {
    if (k0 + 32 < 256) STGH(cur ^ 1, k0 + 32);
    bf16x8 af = *(const bf16x8*)&h1[wr + fr][k0 + fq * 8];
#pragma unroll
    for (int n = 0; n < 16; ++n) {
      bf16x8 bq = *(const bf16x8*)&Bs[cur][n * 16 + fr][fq * 8];
      acc[n] = __builtin_amdgcn_mfma_f32_16x16x32_bf16(af, bq, acc[n], 0, 0, 0);
    }
    __syncthreads();
    cur ^= 1;
  }
#undef STGH
  float cb[16], w0[16], w1[16], w2[16];
#pragma unroll
  for (int n = 0; n < 16; ++n) {
    int col = n * 16 + fr;
    cb[n] = bn1[col];
    w0[n] = Wn2[col * 3 + 0];
    w1[n] = Wn2[col * 3 + 1];
    w2[n] = Wn2[col * 3 + 2];
  }
#pragma unroll
  for (int j = 0; j < 4; ++j) {
    float p0 = 0.f, p1 = 0.f, p2 = 0.f;
#pragma unroll
    for (int n = 0; n < 16; ++n) {
      float h = fmaxf(acc[n][j] + cb[n], 0.f);
      p0 += h * w0[n]; p1 += h * w1[n]; p2 += h * w2[n];
    }
    p0 = red16(p0); p1 = red16(p1); p2 = red16(p2);
    int gm = bm + wr + fq * 4 + j;
    if (fr == 0 && gm < NN) {
      float l0 = p0 + b2h[0], l1 = p1 + b2h[1], l2 = p2 + b2h[2];
      float m = fmaxf(l0, fmaxf(l1, l2));
      float lse = m + logf(__expf(l0 - m) + __expf(l1 - m) + __expf(l2 - m));
      outf[(size_t)gm * 3 + 0] = l0 - lse;
      outf[(size_t)gm * 3 + 1] = l1 - lse;
      outf[(size_t)gm * 3 + 2] = l2 - lse;
    }
  }
}

// ---------------- pool over per-block partials ----------------
__global__ __launch_bounds__(256) void pool_kernel(const float* __restrict__ partial,
                                                   float* __restrict__ gp_sum,
                                                   int nRows) {
  int c = threadIdx.x;
  float s = 0.f;
  for (int r = blockIdx.x; r < nRows; r += gridDim.x)
    s += partial[(size_t)r * 256 + c];
  atomicAdd(&gp_sum[c], s);
}

// ---------------- graph head (single block) ----------------
__global__ __launch_bounds__(256) void graph_head_kernel(
    const float* __restrict__ gp_sum, const float* __restrict__ Wg1,
    const float* __restrict__ bg1, const float* __restrict__ Wg2,
    const float* __restrict__ bg2, float* __restrict__ outp, float invN) {
  __shared__ float gp[256];
  __shared__ float h1[256];
  __shared__ float lg[2];
  int tid = threadIdx.x;
  gp[tid] = gp_sum[tid] * invN;
  __syncthreads();
  float acc = bg1[tid];
  for (int k = 0; k < 256; ++k) acc += gp[k] * Wg1[k * 256 + tid];
  h1[tid] = fmaxf(acc, 0.f);
  __syncthreads();
  if (tid < 2) {
    float l = bg2[tid];
    for (int c = 0; c < 256; ++c) l += h1[c] * Wg2[c * 2 + tid];
    lg[tid] = l;
  }
  __syncthreads();
  if (tid == 0) {
    float m = fmaxf(lg[0], lg[1]);
    float lse = m + logf(__expf(lg[0] - m) + __expf(lg[1] - m));
    outp[0] = lg[0] - lse;
    outp[1] = lg[1] - lse;
  }
}

// ---------------- launch ----------------
extern "C" void kernel_launch(void* const* d_in, const int* in_sizes, int n_in,
                              void* d_out, int out_size, void* d_ws, size_t ws_size,
                              hipStream_t stream) {
  (void)in_sizes; (void)n_in; (void)out_size; (void)ws_size;
  const float* node_feature = (const float*)d_in[0];
  const int* edge_index = (const int*)d_in[1];
  const float* edge_attr = (const float*)d_in[2];
  const float* Wne = (const float*)d_in[3];
  const float* bne = (const float*)d_in[4];
  const float* Wee = (const float*)d_in[5];
  const float* bee = (const float*)d_in[6];
  const float* W1 = (const float*)d_in[7];
  const float* b1 = (const float*)d_in[8];
  const float* g1 = (const float*)d_in[9];
  const float* be1 = (const float*)d_in[10];
  const float* W2 = (const float*)d_in[11];
  const float* b2 = (const float*)d_in[12];
  const float* dg = (const float*)d_in[13];
  const float* db = (const float*)d_in[14];
  const float* tpar = (const float*)d_in[15];
  const float* Wq_n = (const float*)d_in[16];
  const float* Wk_n = (const float*)d_in[17];
  const float* Wv_n = (const float*)d_in[18];
  const float* gamma_n = (const float*)d_in[19];
  const float* Wn1 = (const float*)d_in[20];
  const float* bn1 = (const float*)d_in[21];
  const float* Wn2 = (const float*)d_in[22];
  const float* bn2 = (const float*)d_in[23];
  const float* Wq_g = (const float*)d_in[24];
  const float* Wk_g = (const float*)d_in[25];
  const float* Wv_g = (const float*)d_in[26];
  const float* gamma_g = (const float*)d_in[27];
  const float* Wg1 = (const float*)d_in[28];
  const float* bg1 = (const float*)d_in[29];
  const float* Wg2 = (const float*)d_in[30];
  const float* bg2 = (const float*)d_in[31];
  float* out = (float*)d_out;

  // ---- workspace carve-out (256B-aligned regions) ----
  char* pc = (char*)d_ws;
  auto alloc = [&](size_t bytes) {
    char* r = pc;
    pc += (bytes + 255) & ~(size_t)255;
    return r;
  };
  float* xbuf = (float*)alloc((size_t)2 * MP * HH * 4);       // f32 residual
  __bf16* hbuf_b = (__bf16*)alloc((size_t)2 * MP * HH * 2);   // LN'd agg input
  float* emb = (float*)alloc((size_t)NN * 2 * HH * 4);        // [N,T,H] f32
  __bf16* aggout_b = (__bf16*)alloc((size_t)2 * MP * HH * 2); // agg out
  float* partial = xbuf;        // alias: graph-attn partials [314][256]
  __bf16* wt_ne = (__bf16*)alloc((size_t)128 * 576 * 2);
  __bf16* wt1 = (__bf16*)alloc((size_t)4 * 256 * 128 * 2);
  __bf16* wt2 = (__bf16*)alloc((size_t)4 * 128 * 256 * 2);
  __bf16* wtn1 = (__bf16*)alloc((size_t)256 * 256 * 2);
  float* gp_sum = (float*)alloc(256 * 4);
  int* deg = (int*)alloc((size_t)2 * NN * 4);
  int* cursor = (int*)alloc((size_t)2 * NN * 4);
  int* rowptr = (int*)alloc((size_t)(2 * NN + 2) * 4);
  Edge* edges = (Edge*)alloc((size_t)2 * EE * 8);

  const int gRows2 = 2 * MP / 64;  // 628 row-blocks, stacked layer kernel

  WtDescs wd;
  int gb = 0;
  wd.d[0] = {Wne, wt_ne, FF, HH, 576, gb}; gb += HH * 576 / 8;
  for (int l = 0; l < 4; ++l) {
    wd.d[1 + l] = {W1 + (size_t)l * HH * 256, wt1 + (size_t)l * 256 * HH, HH, 256,
                   HH, gb};
    gb += 256 * HH / 8;
  }
  for (int l = 0; l < 4; ++l) {
    wd.d[5 + l] = {W2 + (size_t)l * 256 * HH, wt2 + (size_t)l * HH * 256, 256, HH,
                   256, gb};
    gb += HH * 256 / 8;
  }
  wd.d[9] = {Wn1, wtn1, 256, 256, 256, gb};

  // prologue: deg zero; weight converts + degree count + gp_sum zero
  hipMemsetAsync(deg, 0, 2 * NN * sizeof(int), stream);
  prep_kernel<<<(WTG + CTG + 255) / 256, 256, 0, stream>>>(wd, edge_index, deg,
                                                           gp_sum);
  scan2_kernel<<<2, 1024, 0, stream>>>(deg, rowptr, cursor);
  // encoder GEMM (f32 A direct, dup to both halves) + XCD-routed edge scatter
  enc_scatter_kernel<<<ENCB + 8 * SSB, 256, 0, stream>>>(
      node_feature, wt_ne, bne, hbuf_b, edge_index, edge_attr, cursor, edges);

  // layer loop, both ti at once: agg + fused MLP (lin1+LN+relu | lin2+res+LN)
  for (int l = 0; l < LL; ++l) {
    agg_kernel<<<625 * 8, 256, 0, stream>>>(hbuf_b, rowptr, edges, Wee, bee, tpar,
                                            l, aggout_b);
    const __bf16* w1l = wt1 + (size_t)l * 256 * HH;
    const __bf16* w2l = wt2 + (size_t)l * HH * 256;
    if (l == 0)
      gemm_layer<0><<<gRows2, 256, 0, stream>>>(
          aggout_b, w1l, b1 + l * 2 * HH, g1 + l * 2 * HH, be1 + l * 2 * HH, w2l,
          b2 + l * HH, xbuf, dg + 1 * HH, db + 1 * HH, hbuf_b);
    else if (l < LL - 1)
      gemm_layer<1><<<gRows2, 256, 0, stream>>>(
          aggout_b, w1l, b1 + l * 2 * HH, g1 + l * 2 * HH, be1 + l * 2 * HH, w2l,
          b2 + l * HH, xbuf, dg + (l + 1) * HH, db + (l + 1) * HH, hbuf_b);
    else
      gemm_layer<2><<<gRows2, 256, 0, stream>>>(
          aggout_b, w1l, b1 + l * 2 * HH, g1 + l * 2 * HH, be1 + l * 2 * HH, w2l,
          b2 + l * HH, xbuf, dg, db, emb);
  }

  // fused attention + node head (+ graph partials in one pass)
  attn_head_kernel<<<MP / 64, 256, 0, stream>>>(
      emb, Wq_n, Wk_n, Wv_n, gamma_n, Wq_g, Wk_g, Wv_g, gamma_g, wtn1, bn1, Wn2,
      bn2, out, partial);
  // graph head
  pool_kernel<<<128, 256, 0, stream>>>(partial, gp_sum, MP / 64);
  graph_head_kernel<<<1, 256, 0, stream>>>(gp_sum, Wg1, bg1, Wg2, bg2,
                                           out + (size_t)NN * CN, 1.0f / NN);
}